// Round 1
// baseline (16311.098 us; speedup 1.0000x reference)
//
#include <hip/hip_runtime.h>
#include <math.h>

#define Bb 64
#define Tt 256
#define Vv 4096
#define Ee 512
#define Hh 1024

// ---------------- weight transpose (H-part): WT[k][col_off+n] = W[n][512+k] ----------
__global__ __launch_bounds__(256) void k_transpose(const float* __restrict__ W,
                                                   float* __restrict__ WT,
                                                   int out_stride, int col_off) {
  __shared__ float tile[32][33];
  int tx = threadIdx.x & 31;
  int ty = threadIdx.x >> 5;
  int bx = blockIdx.x, by = blockIdx.y;
#pragma unroll
  for (int i = 0; i < 4; ++i) {
    int n = by * 32 + ty + i * 8;
    tile[ty + i * 8][tx] = W[n * 1536 + 512 + bx * 32 + tx];
  }
  __syncthreads();
#pragma unroll
  for (int i = 0; i < 4; ++i) {
    int k = bx * 32 + ty + i * 8;
    WT[k * out_stride + col_off + by * 32 + tx] = tile[tx][ty + i * 8];
  }
}

// ---------------- input projection: AtT[t][n][b] = sum_e wte[x[b,t]][e]*W[n][e] + bias[n]
// fp32 tiled GEMM, A rows gathered from wte. BM=BN=128, BK=16, 8x8 microtile.
__global__ __launch_bounds__(256) void k_proj(const int* __restrict__ x,
                                              const float* __restrict__ wte,
                                              const float* __restrict__ W,
                                              const float* __restrict__ bias,
                                              float* __restrict__ AtT) {
  __shared__ float As[16][132];
  __shared__ float Bs[16][132];
  int tid = threadIdx.x;
  int m0 = blockIdx.x * 128;
  int n0 = blockIdx.y * 128;
  int tm = tid & 15, tn = tid >> 4;
  float acc[8][8];
#pragma unroll
  for (int i = 0; i < 8; ++i)
#pragma unroll
    for (int j = 0; j < 8; ++j) acc[i][j] = 0.f;

  for (int k0 = 0; k0 < Ee; k0 += 16) {
#pragma unroll
    for (int p = 0; p < 2; ++p) {
      int id = tid + p * 256;
      int row = id >> 2, c4 = id & 3;
      int m = m0 + row;
      int tok = x[(m & 63) * Tt + (m >> 6)];
      float4 v = *(const float4*)(wte + tok * Ee + k0 + c4 * 4);
      As[c4 * 4 + 0][row] = v.x; As[c4 * 4 + 1][row] = v.y;
      As[c4 * 4 + 2][row] = v.z; As[c4 * 4 + 3][row] = v.w;
    }
#pragma unroll
    for (int p = 0; p < 2; ++p) {
      int id = tid + p * 256;
      int row = id >> 2, c4 = id & 3;
      float4 v = *(const float4*)(W + (n0 + row) * 1536 + k0 + c4 * 4);
      Bs[c4 * 4 + 0][row] = v.x; Bs[c4 * 4 + 1][row] = v.y;
      Bs[c4 * 4 + 2][row] = v.z; Bs[c4 * 4 + 3][row] = v.w;
    }
    __syncthreads();
#pragma unroll
    for (int kk = 0; kk < 16; ++kk) {
      float4 a0 = *(const float4*)&As[kk][tm * 8];
      float4 a1 = *(const float4*)&As[kk][tm * 8 + 4];
      float4 b0 = *(const float4*)&Bs[kk][tn * 8];
      float4 b1 = *(const float4*)&Bs[kk][tn * 8 + 4];
      float av[8] = {a0.x, a0.y, a0.z, a0.w, a1.x, a1.y, a1.z, a1.w};
      float bv[8] = {b0.x, b0.y, b0.z, b0.w, b1.x, b1.y, b1.z, b1.w};
#pragma unroll
      for (int i = 0; i < 8; ++i)
#pragma unroll
        for (int j = 0; j < 8; ++j)
          acc[i][j] = fmaf(av[i], bv[j], acc[i][j]);
    }
    __syncthreads();
  }
#pragma unroll
  for (int i = 0; i < 8; ++i) {
    int m = m0 + tm * 8 + i;
    int t = m >> 6, b = m & 63;
#pragma unroll
    for (int j = 0; j < 8; ++j) {
      int n = n0 + tn * 8 + j;
      AtT[t * (Hh * Bb) + n * Bb + b] = acc[i][j] + bias[n];
    }
  }
}

// ---------------- head GEMM: C[m][n] = sum_k hidden[m][k]*Whead[n][k] + bhead[n] -------
__global__ __launch_bounds__(256) void k_head(const float* __restrict__ A,
                                              const float* __restrict__ W,
                                              const float* __restrict__ bias,
                                              float* __restrict__ C) {
  __shared__ float As[16][132];
  __shared__ float Bs[16][132];
  int tid = threadIdx.x;
  int m0 = blockIdx.x * 128;
  int n0 = blockIdx.y * 128;
  int tm = tid & 15, tn = tid >> 4;
  float acc[8][8];
#pragma unroll
  for (int i = 0; i < 8; ++i)
#pragma unroll
    for (int j = 0; j < 8; ++j) acc[i][j] = 0.f;

  for (int k0 = 0; k0 < Hh; k0 += 16) {
#pragma unroll
    for (int p = 0; p < 2; ++p) {
      int id = tid + p * 256;
      int row = id >> 2, c4 = id & 3;
      float4 v = *(const float4*)(A + (m0 + row) * Hh + k0 + c4 * 4);
      As[c4 * 4 + 0][row] = v.x; As[c4 * 4 + 1][row] = v.y;
      As[c4 * 4 + 2][row] = v.z; As[c4 * 4 + 3][row] = v.w;
    }
#pragma unroll
    for (int p = 0; p < 2; ++p) {
      int id = tid + p * 256;
      int row = id >> 2, c4 = id & 3;
      float4 v = *(const float4*)(W + (n0 + row) * Hh + k0 + c4 * 4);
      Bs[c4 * 4 + 0][row] = v.x; Bs[c4 * 4 + 1][row] = v.y;
      Bs[c4 * 4 + 2][row] = v.z; Bs[c4 * 4 + 3][row] = v.w;
    }
    __syncthreads();
#pragma unroll
    for (int kk = 0; kk < 16; ++kk) {
      float4 a0 = *(const float4*)&As[kk][tm * 8];
      float4 a1 = *(const float4*)&As[kk][tm * 8 + 4];
      float4 b0 = *(const float4*)&Bs[kk][tn * 8];
      float4 b1 = *(const float4*)&Bs[kk][tn * 8 + 4];
      float av[8] = {a0.x, a0.y, a0.z, a0.w, a1.x, a1.y, a1.z, a1.w};
      float bv[8] = {b0.x, b0.y, b0.z, b0.w, b1.x, b1.y, b1.z, b1.w};
#pragma unroll
      for (int i = 0; i < 8; ++i)
#pragma unroll
        for (int j = 0; j < 8; ++j)
          acc[i][j] = fmaf(av[i], bv[j], acc[i][j]);
    }
    __syncthreads();
  }
#pragma unroll
  for (int i = 0; i < 8; ++i) {
    int m = m0 + tm * 8 + i;
#pragma unroll
    for (int jj = 0; jj < 2; ++jj) {
      int n = n0 + tn * 8 + jj * 4;
      float4 v;
      v.x = acc[i][jj * 4 + 0] + bias[n + 0];
      v.y = acc[i][jj * 4 + 1] + bias[n + 1];
      v.z = acc[i][jj * 4 + 2] + bias[n + 2];
      v.w = acc[i][jj * 4 + 3] + bias[n + 3];
      *(float4*)&C[m * Vv + n] = v;
    }
  }
}

// ---------------- init: preact buffers for t=0, hT broadcast of start ------------------
__global__ __launch_bounds__(256) void k_init(float* __restrict__ rz0,
                                              float* __restrict__ hb0,
                                              float* __restrict__ hT,
                                              const float* __restrict__ AtT_r,
                                              const float* __restrict__ AtT_z,
                                              const float* __restrict__ AtT_b,
                                              const float* __restrict__ start) {
  int g = blockIdx.x * 256 + threadIdx.x;   // grid 1024*256 = 262144
  if (g < 65536) {
    rz0[g] = AtT_r[g];
  } else if (g < 131072) {
    rz0[g] = AtT_z[g - 65536];
  } else if (g < 196608) {
    hb0[g - 131072] = AtT_b[g - 131072];
  } else {
    int i = g - 196608;
    hT[i] = start[i >> 6];
  }
}

// ---------------- recurrence phase A: r/z GEMM partials ---------------------------------
// wave = 64 lanes = 64 batches; wave covers 64 output cols n; k-slice of 32.
// preact_rzT[n][b] += sum_{k in slice} WT_rz[k][n] * hT[k][b]
__global__ __launch_bounds__(256) void k_rz(const float* __restrict__ hT,
                                            const float* __restrict__ WT_rz,
                                            float* __restrict__ preact) {
  int lane = threadIdx.x & 63;
  int wv = __builtin_amdgcn_readfirstlane((int)(threadIdx.x >> 6));
  int ks = blockIdx.x & 31;
  int ng = blockIdx.x >> 5;          // 0..7
  int n0 = ng * 256 + wv * 64;
  int k0 = ks * 32;
  float acc[64];
#pragma unroll
  for (int n = 0; n < 64; ++n) acc[n] = 0.f;
  for (int kk = 0; kk < 32; ++kk) {
    int k = k0 + kk;
    float vh = hT[k * 64 + lane];
    const float* wrow = WT_rz + k * 2048 + n0;
#pragma unroll
    for (int n = 0; n < 64; ++n) acc[n] = fmaf(wrow[n], vh, acc[n]);
  }
#pragma unroll
  for (int n = 0; n < 64; ++n)
    atomicAdd(&preact[(n0 + n) * 64 + lane], acc[n]);
}

// ---------------- recurrence phase B: rh = sigmoid(pre_r)*h (LDS), hbar GEMM partials ---
__global__ __launch_bounds__(256) void k_hbar(const float* __restrict__ hT,
                                              const float* __restrict__ rz_cur,
                                              const float* __restrict__ WT_bar,
                                              float* __restrict__ preact_hb) {
  __shared__ float rhs[32 * 64];
  int tid = threadIdx.x;
  int lane = tid & 63;
  int ks = blockIdx.x & 31;
  int ng = blockIdx.x >> 5;          // 0..3
  int k0 = ks * 32;
  for (int i = tid; i < 2048; i += 256) {
    int kl = i >> 6, b = i & 63;
    int row = k0 + kl;
    float pr = rz_cur[row * 64 + b];
    float r = 1.f / (1.f + expf(-pr));
    rhs[kl * 64 + b] = r * hT[row * 64 + b];
  }
  __syncthreads();
  int wv = __builtin_amdgcn_readfirstlane((int)(tid >> 6));
  int n0 = ng * 256 + wv * 64;
  float acc[64];
#pragma unroll
  for (int n = 0; n < 64; ++n) acc[n] = 0.f;
  for (int kk = 0; kk < 32; ++kk) {
    float vrh = rhs[kk * 64 + lane];
    const float* wrow = WT_bar + (k0 + kk) * 1024 + n0;
#pragma unroll
    for (int n = 0; n < 64; ++n) acc[n] = fmaf(wrow[n], vrh, acc[n]);
  }
#pragma unroll
  for (int n = 0; n < 64; ++n)
    atomicAdd(&preact_hb[(n0 + n) * 64 + lane], acc[n]);
}

// ---------------- recurrence phase C: h update + hidden write + next preact init --------
__global__ __launch_bounds__(256) void k_update(const float* __restrict__ rz_cur,
                                                const float* __restrict__ hb_cur,
                                                float* __restrict__ rz_next,
                                                float* __restrict__ hb_next,
                                                float* __restrict__ hT,
                                                float* __restrict__ hidden,
                                                const float* __restrict__ AtT_r,
                                                const float* __restrict__ AtT_z,
                                                const float* __restrict__ AtT_b,
                                                int t) {
  __shared__ float lt[16][65];
  int tid = threadIdx.x;
  int lane = tid & 63;
  int q = tid >> 6;                  // 0..3
  int n0 = blockIdx.x * 16;
#pragma unroll
  for (int j = 0; j < 4; ++j) {
    int nl = q * 4 + j;
    int n = n0 + nl;
    float pz = rz_cur[(1024 + n) * 64 + lane];
    float ph = hb_cur[n * 64 + lane];
    float ho = hT[n * 64 + lane];
    float z = 1.f / (1.f + expf(-pz));
    float hb = tanhf(ph);
    float hn = ho + z * (hb - ho);
    hT[n * 64 + lane] = hn;
    lt[nl][lane] = hn;
  }
  if (t + 1 < Tt) {
    const float* ar = AtT_r + (t + 1) * 65536;
    const float* az = AtT_z + (t + 1) * 65536;
    const float* ab = AtT_b + (t + 1) * 65536;
    int r0 = blockIdx.x * 32;
    for (int i = tid; i < 32 * 64; i += 256) {
      int row = r0 + (i >> 6), b = i & 63;
      float v = (row < 1024) ? ar[row * 64 + b] : az[(row - 1024) * 64 + b];
      rz_next[row * 64 + b] = v;
    }
    int rh0 = blockIdx.x * 16;
    for (int i = tid; i < 16 * 64; i += 256) {
      int row = rh0 + (i >> 6), b = i & 63;
      hb_next[row * 64 + b] = ab[row * 64 + b];
    }
  }
  __syncthreads();
  int b2 = tid >> 2, qq = tid & 3;
  float4 v;
  v.x = lt[qq * 4 + 0][b2];
  v.y = lt[qq * 4 + 1][b2];
  v.z = lt[qq * 4 + 2][b2];
  v.w = lt[qq * 4 + 3][b2];
  *(float4*)&hidden[b2 * (Tt * Hh) + t * Hh + n0 + qq * 4] = v;
}

extern "C" void kernel_launch(void* const* d_in, const int* in_sizes, int n_in,
                              void* d_out, int out_size, void* d_ws, size_t ws_size,
                              hipStream_t stream) {
  (void)in_sizes; (void)n_in; (void)out_size; (void)ws_size;
  const int*   x     = (const int*)  d_in[0];
  const float* start = (const float*)d_in[1];
  const float* wte   = (const float*)d_in[2];
  const float* Wr    = (const float*)d_in[3];
  const float* br    = (const float*)d_in[4];
  const float* Wbar  = (const float*)d_in[5];
  const float* bbar  = (const float*)d_in[6];
  const float* Wz    = (const float*)d_in[7];
  const float* bz    = (const float*)d_in[8];
  const float* Whead = (const float*)d_in[9];
  const float* bhead = (const float*)d_in[10];
  float* out = (float*)d_out;

  float* p = (float*)d_ws;
  float* AtT_r  = p; p += (size_t)Tt * Hh * Bb;   // 16.8M floats
  float* AtT_z  = p; p += (size_t)Tt * Hh * Bb;
  float* AtT_b  = p; p += (size_t)Tt * Hh * Bb;
  float* hidden = p; p += (size_t)Bb * Tt * Hh;
  float* WT_rz  = p; p += (size_t)1024 * 2048;
  float* WT_bar = p; p += (size_t)1024 * 1024;
  float* hT     = p; p += 65536;
  float* rz0    = p; p += 2048 * 64;
  float* rz1    = p; p += 2048 * 64;
  float* hb0    = p; p += 65536;
  float* hb1    = p; p += 65536;

  dim3 b256(256);
  k_transpose<<<dim3(32, 32), b256, 0, stream>>>(Wr,   WT_rz,  2048, 0);
  k_transpose<<<dim3(32, 32), b256, 0, stream>>>(Wz,   WT_rz,  2048, 1024);
  k_transpose<<<dim3(32, 32), b256, 0, stream>>>(Wbar, WT_bar, 1024, 0);
  k_proj<<<dim3(128, 8), b256, 0, stream>>>(x, wte, Wr,   br,   AtT_r);
  k_proj<<<dim3(128, 8), b256, 0, stream>>>(x, wte, Wz,   bz,   AtT_z);
  k_proj<<<dim3(128, 8), b256, 0, stream>>>(x, wte, Wbar, bbar, AtT_b);
  k_init<<<dim3(1024), b256, 0, stream>>>(rz0, hb0, hT, AtT_r, AtT_z, AtT_b, start);

  for (int t = 0; t < Tt; ++t) {
    float* rzc = (t & 1) ? rz1 : rz0;
    float* rzn = (t & 1) ? rz0 : rz1;
    float* hbc = (t & 1) ? hb1 : hb0;
    float* hbn = (t & 1) ? hb0 : hb1;
    k_rz<<<dim3(256), b256, 0, stream>>>(hT, WT_rz, rzc);
    k_hbar<<<dim3(128), b256, 0, stream>>>(hT, rzc, WT_bar, hbc);
    k_update<<<dim3(64), b256, 0, stream>>>(rzc, hbc, rzn, hbn, hT, hidden,
                                            AtT_r, AtT_z, AtT_b, t);
  }

  k_head<<<dim3(128, 32), b256, 0, stream>>>(hidden, Whead, bhead, out);
}